// Round 1
// baseline (410.558 us; speedup 1.0000x reference)
//
#include <hip/hip_runtime.h>

#define EPS_ 1.1920928955078125e-07f
#define SCALE_ 0.17677669529663687f   // 1/sqrt(32)

// ---------------------------------------------------------------------------
// K1: 3x3 conv, C=128 -> 128, 128x128 spatial, zero-pad SAME.
// Grid (8,8,16): 16x16 spatial tile, 8 output channels per block.
// Each thread: 2 och x 4 px (contiguous quad).
// ---------------------------------------------------------------------------
__global__ __launch_bounds__(256) void conv3x3_k(const float* __restrict__ qin,
                                                 const float* __restrict__ w,
                                                 float* __restrict__ qc) {
  const int tx = blockIdx.x, ty = blockIdx.y, ozg = blockIdx.z;
  const int tid = threadIdx.x;
  __shared__ float in_t[16 * 18 * 20];   // [ic][row 0..17][col 0..19(pad)]
  __shared__ float w_t[8 * 16 * 12];     // [oc][ic][9 used of 12]

  const int qd = tid & 63;           // pixel-quad id
  const int p0 = (qd & 3) * 4;       // x0 within tile
  const int py = qd >> 2;            // row within tile
  const int og = tid >> 6;           // och pair base = og*2

  float acc[2][4];
#pragma unroll
  for (int a = 0; a < 2; a++)
#pragma unroll
    for (int b = 0; b < 4; b++) acc[a][b] = 0.f;

  const int gybase = ty * 16 - 1, gxbase = tx * 16 - 1;

  for (int ic0 = 0; ic0 < 128; ic0 += 16) {
    for (int i = tid; i < 16 * 324; i += 256) {
      int ic = i / 324, r = i - ic * 324;
      int ly = r / 18, lx = r - ly * 18;
      int gy = gybase + ly, gx = gxbase + lx;
      float v = 0.f;
      if (gy >= 0 && gy < 128 && gx >= 0 && gx < 128)
        v = qin[(ic0 + ic) * 16384 + gy * 128 + gx];
      in_t[(ic * 18 + ly) * 20 + lx] = v;
    }
    for (int i = tid; i < 1152; i += 256) {
      int oc = i / 144, r = i - oc * 144;
      int ic = r / 9, kk = r - ic * 9;
      w_t[(oc * 16 + ic) * 12 + kk] = w[(ozg * 8 + oc) * 1152 + (ic0 + ic) * 9 + kk];
    }
    __syncthreads();

    for (int ic = 0; ic < 16; ic++) {
      float cr[3][8];
#pragma unroll
      for (int dy = 0; dy < 3; dy++) {
        const float* rowp = &in_t[(ic * 18 + py + dy) * 20 + p0];
        float4 a = *(const float4*)rowp;
        float4 b = *(const float4*)(rowp + 4);
        cr[dy][0] = a.x; cr[dy][1] = a.y; cr[dy][2] = a.z; cr[dy][3] = a.w;
        cr[dy][4] = b.x; cr[dy][5] = b.y; cr[dy][6] = b.z; cr[dy][7] = b.w;
      }
#pragma unroll
      for (int o2 = 0; o2 < 2; o2++) {
        const float* wp = &w_t[((og * 2 + o2) * 16 + ic) * 12];
        float4 wa = *(const float4*)wp;
        float4 wb = *(const float4*)(wp + 4);
        float wv[9] = {wa.x, wa.y, wa.z, wa.w, wb.x, wb.y, wb.z, wb.w, wp[8]};
#pragma unroll
        for (int p = 0; p < 4; p++) {
          float s = 0.f;
#pragma unroll
          for (int dy = 0; dy < 3; dy++)
#pragma unroll
            for (int dx = 0; dx < 3; dx++)
              s += wv[dy * 3 + dx] * cr[dy][p + dx];
          acc[o2][p] += s;
        }
      }
    }
    __syncthreads();
  }

  const int gy = ty * 16 + py;
  const int gx0 = tx * 16 + p0;
#pragma unroll
  for (int o2 = 0; o2 < 2; o2++) {
    float4 st = {acc[o2][0], acc[o2][1], acc[o2][2], acc[o2][3]};
    *(float4*)&qc[(ozg * 8 + og * 2 + o2) * 16384 + gy * 128 + gx0] = st;
  }
}

// ---------------------------------------------------------------------------
// K2: fused RMSNorm (over channels) + 1x1 projection with bias.
// y[o,p] = b[o] + rs(p) * sum_c W[o,c]*nw[c]*x[c,p]
// One block per 32-pixel chunk; W*nw staged in LDS (128x129).
// ---------------------------------------------------------------------------
__global__ __launch_bounds__(256) void rms_proj_k(const float* __restrict__ x,
                                                  const float* __restrict__ W,
                                                  const float* __restrict__ nw,
                                                  const float* __restrict__ bias,
                                                  float* __restrict__ y,
                                                  int N) {
  __shared__ float Wn[128 * 129];
  __shared__ float x_l[128 * 32];
  __shared__ float y_l[128 * 33];
  __shared__ float pms[8 * 32];
  __shared__ float rs_l[32];
  const int tid = threadIdx.x;

  for (int i = tid; i < 16384; i += 256) {
    int o = i >> 7, c = i & 127;
    Wn[o * 129 + c] = W[i] * nw[c];
  }
  const int px0 = blockIdx.x * 32;
  for (int i = tid; i < 128 * 32; i += 256) {
    int c = i >> 5, px = i & 31;
    x_l[c * 32 + px] = x[c * N + px0 + px];
  }
  __syncthreads();
  {
    int px = tid & 31, seg = tid >> 5;
    float s = 0.f;
    for (int c = seg * 16; c < seg * 16 + 16; c++) {
      float v = x_l[c * 32 + px];
      s += v * v;
    }
    pms[seg * 32 + px] = s;
  }
  __syncthreads();
  if (tid < 32) {
    float s = 0.f;
    for (int seg = 0; seg < 8; seg++) s += pms[seg * 32 + tid];
    rs_l[tid] = rsqrtf(s * (1.0f / 128.0f) + EPS_);
  }
  __syncthreads();

  const int o = tid & 127, h = tid >> 7;
  float acc[4][4];
#pragma unroll
  for (int a = 0; a < 4; a++)
#pragma unroll
    for (int b = 0; b < 4; b++) acc[a][b] = 0.f;

  for (int c = 0; c < 128; c++) {
    float wv = Wn[o * 129 + c];
#pragma unroll
    for (int qd = 0; qd < 4; qd++) {
      float4 xv = *(const float4*)&x_l[c * 32 + h * 16 + qd * 4];
      acc[qd][0] += wv * xv.x;
      acc[qd][1] += wv * xv.y;
      acc[qd][2] += wv * xv.z;
      acc[qd][3] += wv * xv.w;
    }
  }
  float bo = bias[o];
#pragma unroll
  for (int qd = 0; qd < 4; qd++)
#pragma unroll
    for (int p = 0; p < 4; p++) {
      int px = h * 16 + qd * 4 + p;
      y_l[o * 33 + px] = bo + rs_l[px] * acc[qd][p];
    }
  __syncthreads();
  for (int i = tid; i < 128 * 32; i += 256) {
    int oo = i >> 5, px = i & 31;
    y[oo * N + px0 + px] = y_l[oo * 33 + px];
  }
}

// ---------------------------------------------------------------------------
// K3: NATTEN attention. dilation(4) == upsample(4) => the 49 keys of a query
// form a contiguous 7x7 window in the 32x32 k/v grid, shared by each 4x4
// query cell. One block per cell (grid 32x32). Softmax per (q,head) by one
// wave; head-mean folded before the V contraction.
// ---------------------------------------------------------------------------
__global__ __launch_bounds__(256) void natten_k(const float* __restrict__ qp,
                                                const float* __restrict__ kp,
                                                const float* __restrict__ v,
                                                float* __restrict__ out) {
  const int cx = blockIdx.x, cy = blockIdx.y;
  const int tid = threadIdx.x;
  __shared__ float q_l[16 * 129];
  __shared__ float k_l[49 * 129];
  __shared__ float v_l[49 * 129];
  __shared__ float att_l[4 * 64];
  __shared__ float am_l[49];
  __shared__ float ph_l[128];
  __shared__ float o_t[128 * 17];

  const int qy0 = cy * 4, qx0 = cx * 4;
  const int ky0 = (cy < 3) ? 0 : ((cy > 28) ? 25 : cy - 3);
  const int kx0 = (cx < 3) ? 0 : ((cx > 28) ? 25 : cx - 3);

  for (int i = tid; i < 2048; i += 256) {
    int c = i >> 4, j = i & 15;
    q_l[j * 129 + c] = qp[c * 16384 + (qy0 + (j >> 2)) * 128 + qx0 + (j & 3)];
  }
  for (int i = tid; i < 128 * 64; i += 256) {
    int c = i >> 6, t6 = i & 63;
    int m = t6 >> 3, n = t6 & 7;
    if (m < 7 && n < 7) {
      int gaddr = c * 1024 + (ky0 + m) * 32 + kx0 + n;
      k_l[(m * 7 + n) * 129 + c] = kp[gaddr];
      v_l[(m * 7 + n) * 129 + c] = v[gaddr];
    }
  }
  __syncthreads();

  const int h = tid >> 6, kpos = tid & 63;
  const int c_o = tid & 127, half = tid >> 7;

  for (int q = 0; q < 16; q++) {
    float logit = -1e30f;
    if (kpos < 49) {
      float s = 0.f;
      const float* qq = &q_l[q * 129 + h * 32];
      const float* kk = &k_l[kpos * 129 + h * 32];
#pragma unroll
      for (int d = 0; d < 32; d++) s += qq[d] * kk[d];
      logit = s * SCALE_;
    }
    float m = logit;
#pragma unroll
    for (int off = 32; off > 0; off >>= 1) m = fmaxf(m, __shfl_xor(m, off, 64));
    float p = (kpos < 49) ? __expf(logit - m) : 0.f;
    float ssum = p;
#pragma unroll
    for (int off = 32; off > 0; off >>= 1) ssum += __shfl_xor(ssum, off, 64);
    att_l[h * 64 + kpos] = p / ssum;
    __syncthreads();
    if (tid < 49)
      am_l[tid] = 0.25f * (att_l[tid] + att_l[64 + tid] + att_l[128 + tid] + att_l[192 + tid]);
    __syncthreads();
    {
      float s = 0.f;
      int k0 = half ? 25 : 0, k1 = half ? 49 : 25;
      for (int kk = k0; kk < k1; kk++) s += am_l[kk] * v_l[kk * 129 + c_o];
      if (half) ph_l[c_o] = s;
      __syncthreads();
      if (!half) o_t[c_o * 17 + q] = s + ph_l[c_o];
    }
    __syncthreads();
  }

  for (int i = tid; i < 2048; i += 256) {
    int c = i >> 4, j = i & 15;
    out[c * 16384 + (qy0 + (j >> 2)) * 128 + qx0 + (j & 3)] = o_t[c * 17 + j];
  }
}

// ---------------------------------------------------------------------------
extern "C" void kernel_launch(void* const* d_in, const int* in_sizes, int n_in,
                              void* d_out, int out_size, void* d_ws, size_t ws_size,
                              hipStream_t stream) {
  const float* q_in    = (const float*)d_in[0];   // [128,128,128]
  const float* k_in    = (const float*)d_in[1];   // [128,32,32]
  const float* v_in    = (const float*)d_in[2];   // [128,32,32]
  const float* conv_w  = (const float*)d_in[3];   // [128,128,3,3]
  const float* normq_w = (const float*)d_in[4];   // [128]
  const float* normk_w = (const float*)d_in[5];   // [128]
  const float* qproj_w = (const float*)d_in[6];   // [128,128]
  const float* qproj_b = (const float*)d_in[7];   // [128]
  const float* kproj_w = (const float*)d_in[8];   // [128,128]
  const float* kproj_b = (const float*)d_in[9];   // [128]
  float* out = (float*)d_out;                      // [128,128,128]

  float* ws = (float*)d_ws;
  float* qc = ws;                  // conv output  [128,16384]
  float* qp = ws + 2097152;        // q projected  [128,16384]
  float* kp = ws + 4194304;        // k projected  [128,1024]

  conv3x3_k<<<dim3(8, 8, 16), 256, 0, stream>>>(q_in, conv_w, qc);
  rms_proj_k<<<dim3(512), 256, 0, stream>>>(qc, qproj_w, normq_w, qproj_b, qp, 16384);
  rms_proj_k<<<dim3(32), 256, 0, stream>>>(k_in, kproj_w, normk_w, kproj_b, kp, 1024);
  natten_k<<<dim3(32, 32), 256, 0, stream>>>(qp, kp, v_in, out);
}

// Round 2
// 146.217 us; speedup vs baseline: 2.8079x; 2.8079x over previous
//
#include <hip/hip_runtime.h>

#define EPS_ 1.1920928955078125e-07f
#define SCALE_ 0.17677669529663687f   // 1/sqrt(32)

typedef __attribute__((ext_vector_type(8))) short s8b;     // 8 bf16 (16B)
typedef __attribute__((ext_vector_type(4))) float f32x4;   // MFMA acc
typedef __attribute__((ext_vector_type(4))) int int4v;     // 16B staging

static __device__ __forceinline__ unsigned short f2bf(float f) {
  unsigned int u = __float_as_uint(f);
  unsigned int r = (u + 0x7fffu + ((u >> 16) & 1u)) >> 16;   // RNE
  return (unsigned short)r;
}
static __device__ __forceinline__ float b2f(unsigned short h) {
  return __uint_as_float(((unsigned int)h) << 16);
}
static __device__ __forceinline__ float b2fs(short h) {
  return __uint_as_float(((unsigned int)(unsigned short)h) << 16);
}

// ---------------------------------------------------------------------------
// zero the halo border of qb [130][130][128] bf16
// ---------------------------------------------------------------------------
__global__ void zerob_k(unsigned short* __restrict__ qb) {
  int gid = blockIdx.x * 256 + threadIdx.x;   // grid 9 -> 2304 threads
  s8b z = {0, 0, 0, 0, 0, 0, 0, 0};
  for (int j = gid; j < 2080; j += 2304) {            // rows 0 and 129
    *(s8b*)&qb[j * 8] = z;
    *(s8b*)&qb[129 * 130 * 128 + j * 8] = z;
  }
  for (int j = gid; j < 2048; j += 2304) {            // cols 0 and 129, rows 1..128
    int r = (j >> 4) + 1, s = j & 15;
    *(s8b*)&qb[(r * 130) * 128 + s * 8] = z;
    *(s8b*)&qb[(r * 130 + 129) * 128 + s * 8] = z;
  }
}

// ---------------------------------------------------------------------------
// fp32 NCHW [128][N] -> bf16 NHWC [..][128] with optional per-row pad shift
// out pixel index = px + padamt*(px>>lw) + off
// ---------------------------------------------------------------------------
__global__ __launch_bounds__(256) void transpose_k(const float* __restrict__ in,
                                                   unsigned short* __restrict__ outp,
                                                   int N, int lw, int padamt, int off) {
  __shared__ unsigned short t_l[64 * 136];
  const int tid = threadIdx.x;
  const int px0 = blockIdx.x * 64;
  for (int i = tid; i < 8192; i += 256) {
    int c = i >> 6, p = i & 63;
    t_l[p * 136 + c] = f2bf(in[c * N + px0 + p]);
  }
  __syncthreads();
  for (int i = tid; i < 1024; i += 256) {
    int p = i >> 4, s = i & 15;
    int px = px0 + p;
    int opx = px + padamt * (px >> lw) + off;
    *(s8b*)&outp[opx * 128 + s * 8] = *(const s8b*)&t_l[p * 136 + s * 8];
  }
}

// ---------------------------------------------------------------------------
// pack conv weights -> wb [9][4][128][40] bf16, and Wnq=[128][136] bf16
// ---------------------------------------------------------------------------
__global__ void packw_k(const float* __restrict__ cw, const float* __restrict__ qw,
                        const float* __restrict__ nqw,
                        unsigned short* __restrict__ wb, unsigned short* __restrict__ wnq) {
  int idx = blockIdx.x * 256 + threadIdx.x;
  if (idx < 184320) {
    int i40 = idx % 40;
    int r = idx / 40;
    int oc = r & 127, r2 = r >> 7;
    int kc = r2 & 3, t = r2 >> 2;
    float v = 0.f;
    if (i40 < 32) v = cw[oc * 1152 + (kc * 32 + i40) * 9 + t];
    wb[idx] = f2bf(v);
  } else if (idx < 184320 + 17408) {
    int j = idx - 184320;
    int i136 = j % 136;
    int o = j / 136;
    float v = (i136 < 128) ? qw[o * 128 + i136] * nqw[i136] : 0.f;
    wnq[j] = f2bf(v);
  }
}

// ---------------------------------------------------------------------------
// k-side: fp32 RMSNorm + 1x1 proj, output bf16 NHWC [1024][128]
// ---------------------------------------------------------------------------
__global__ __launch_bounds__(256) void rmsk_k(const float* __restrict__ x,
                                              const float* __restrict__ W,
                                              const float* __restrict__ nw,
                                              const float* __restrict__ bias,
                                              unsigned short* __restrict__ yb) {
  __shared__ float Wn[128 * 129];
  __shared__ float x_l[128 * 32];
  __shared__ float y_l[128 * 33];
  __shared__ float pms[8 * 32];
  __shared__ float rs_l[32];
  const int tid = threadIdx.x;
  const int N = 1024;

  for (int i = tid; i < 16384; i += 256) {
    int o = i >> 7, c = i & 127;
    Wn[o * 129 + c] = W[i] * nw[c];
  }
  const int px0 = blockIdx.x * 32;
  for (int i = tid; i < 128 * 32; i += 256) {
    int c = i >> 5, px = i & 31;
    x_l[c * 32 + px] = x[c * N + px0 + px];
  }
  __syncthreads();
  {
    int px = tid & 31, seg = tid >> 5;
    float s = 0.f;
    for (int c = seg * 16; c < seg * 16 + 16; c++) {
      float v = x_l[c * 32 + px];
      s += v * v;
    }
    pms[seg * 32 + px] = s;
  }
  __syncthreads();
  if (tid < 32) {
    float s = 0.f;
    for (int seg = 0; seg < 8; seg++) s += pms[seg * 32 + tid];
    rs_l[tid] = rsqrtf(s * (1.0f / 128.0f) + EPS_);
  }
  __syncthreads();

  const int o = tid & 127, h = tid >> 7;
  float acc[4][4];
#pragma unroll
  for (int a = 0; a < 4; a++)
#pragma unroll
    for (int b = 0; b < 4; b++) acc[a][b] = 0.f;

  for (int c = 0; c < 128; c++) {
    float wv = Wn[o * 129 + c];
#pragma unroll
    for (int qd = 0; qd < 4; qd++) {
      float4 xv = *(const float4*)&x_l[c * 32 + h * 16 + qd * 4];
      acc[qd][0] += wv * xv.x;
      acc[qd][1] += wv * xv.y;
      acc[qd][2] += wv * xv.z;
      acc[qd][3] += wv * xv.w;
    }
  }
  float bo = bias[o];
#pragma unroll
  for (int qd = 0; qd < 4; qd++)
#pragma unroll
    for (int p = 0; p < 4; p++) {
      int px = h * 16 + qd * 4 + p;
      y_l[o * 33 + px] = bo + rs_l[px] * acc[qd][p];
    }
  __syncthreads();
  for (int i = tid; i < 4096; i += 256) {
    int px = i >> 7, o2 = i & 127;
    yb[(px0 + px) * 128 + o2] = f2bf(y_l[o2 * 33 + px]);
  }
}

// ---------------------------------------------------------------------------
// conv3x3 (implicit GEMM, bf16 MFMA) + fused RMSNorm + qproj.
// Grid 512: block = row y = bx>>2, px x0=(bx&3)*32. Output: qpb bf16 NHWC.
// LDS: conv phase:  in_l[3][34][136] @0 (27744B) | wbuf 2x[128][40] @27744 (20480B)
//      proj phase:  wnq_l[128][136] @0 (34816B)  | qc_l[32][136] @34816 (8704B)
//      extras @48224: rs(128) red(1024) bq(512)
// ---------------------------------------------------------------------------
__global__ __launch_bounds__(256, 2) void conv_fused_k(
    const unsigned short* __restrict__ qb, const unsigned short* __restrict__ wb,
    const unsigned short* __restrict__ wnq, const float* __restrict__ qbias,
    unsigned short* __restrict__ qpb) {
  __shared__ __align__(16) char smem[49888];
  unsigned short* in_l = (unsigned short*)smem;
  unsigned short* wbuf = (unsigned short*)(smem + 27744);
  unsigned short* wnq_l = (unsigned short*)smem;
  unsigned short* qc_l = (unsigned short*)(smem + 34816);
  float* rs_l = (float*)(smem + 48224);
  float* red_l = (float*)(smem + 48352);
  float* bq_l = (float*)(smem + 49376);

  const int tid = threadIdx.x;
  const int bx = blockIdx.x;
  const int y = bx >> 2, x0 = (bx & 3) * 32;
  const int w = tid >> 6, lane = tid & 63;
  const int lm = lane & 15, kg = lane >> 4;

  if (tid < 128) bq_l[tid] = qbias[tid];

  // stage input halo [3][34][136]
  for (int i = tid; i < 1632; i += 256) {
    int s16 = i & 15, r = i >> 4;
    int ry = r / 34, lx = r - ry * 34;
    s8b v = *(const s8b*)&qb[(((y + ry) * 130) + x0 + lx) * 128 + s16 * 8];
    *(s8b*)&in_l[(ry * 34 + lx) * 136 + s16 * 8] = v;
  }
  // stage weight chunk 0 (640 x 16B)
  {
    const int4v* src = (const int4v*)wb;
    int4v* dst = (int4v*)wbuf;
    dst[tid] = src[tid];
    dst[tid + 256] = src[tid + 256];
    if (tid < 128) dst[tid + 512] = src[tid + 512];
  }
  __syncthreads();

  f32x4 acc[2][2];
#pragma unroll
  for (int a = 0; a < 2; a++)
#pragma unroll
    for (int b = 0; b < 2; b++) acc[a][b] = (f32x4){0.f, 0.f, 0.f, 0.f};

  for (int s = 0; s < 36; s++) {
    int4v p0, p1, p2;
    const bool pf = (s < 35);
    if (pf) {
      const int4v* src = (const int4v*)(wb + (s + 1) * 5120);
      p0 = src[tid];
      p1 = src[tid + 256];
      if (tid < 128) p2 = src[tid + 512];
    }
    const unsigned short* wcur = wbuf + (s & 1) * 5120;
    const int t = s >> 2, kc = s & 3;
    const int dy = t / 3, dx = t - dy * 3;
    const int ic0 = kc * 32;

    s8b a0 = *(const s8b*)&wcur[((2 * w) * 16 + lm) * 40 + kg * 8];
    s8b a1 = *(const s8b*)&wcur[((2 * w + 1) * 16 + lm) * 40 + kg * 8];
    s8b b0 = *(const s8b*)&in_l[(dy * 34 + lm + dx) * 136 + ic0 + kg * 8];
    s8b b1 = *(const s8b*)&in_l[(dy * 34 + 16 + lm + dx) * 136 + ic0 + kg * 8];
    acc[0][0] = __builtin_amdgcn_mfma_f32_16x16x32_bf16(a0, b0, acc[0][0], 0, 0, 0);
    acc[0][1] = __builtin_amdgcn_mfma_f32_16x16x32_bf16(a0, b1, acc[0][1], 0, 0, 0);
    acc[1][0] = __builtin_amdgcn_mfma_f32_16x16x32_bf16(a1, b0, acc[1][0], 0, 0, 0);
    acc[1][1] = __builtin_amdgcn_mfma_f32_16x16x32_bf16(a1, b1, acc[1][1], 0, 0, 0);

    if (pf) {
      int4v* dst = (int4v*)(wbuf + ((s + 1) & 1) * 5120);
      dst[tid] = p0;
      dst[tid + 256] = p1;
      if (tid < 128) dst[tid + 512] = p2;
    }
    __syncthreads();
  }

  // conv epilogue: tile -> qc_l bf16 [px][c]; stage Wnq over in_l/wbuf
#pragma unroll
  for (int mi = 0; mi < 2; mi++)
#pragma unroll
    for (int nt = 0; nt < 2; nt++)
#pragma unroll
      for (int r = 0; r < 4; r++) {
        int px = nt * 16 + lm;
        int c = (2 * w + mi) * 16 + kg * 4 + r;
        qc_l[px * 136 + c] = f2bf(acc[mi][nt][r]);
      }
  for (int i = tid; i < 2176; i += 256)
    ((int4v*)wnq_l)[i] = ((const int4v*)wnq)[i];
  __syncthreads();

  // rms over channels (on bf16 conv tile)
  {
    int px = tid >> 3, t8 = tid & 7;
    s8b v0 = *(const s8b*)&qc_l[px * 136 + t8 * 16];
    s8b v1 = *(const s8b*)&qc_l[px * 136 + t8 * 16 + 8];
    float ssum = 0.f;
#pragma unroll
    for (int j = 0; j < 8; j++) {
      float f0 = b2fs(v0[j]), f1 = b2fs(v1[j]);
      ssum += f0 * f0 + f1 * f1;
    }
    red_l[px * 8 + t8] = ssum;
  }
  __syncthreads();
  if (tid < 32) {
    float s = 0.f;
#pragma unroll
    for (int j = 0; j < 8; j++) s += red_l[tid * 8 + j];
    rs_l[tid] = rsqrtf(s * (1.0f / 128.0f) + EPS_);
  }
  __syncthreads();

  // qproj GEMM (4 K-steps)
  f32x4 acc2[2][2];
#pragma unroll
  for (int a = 0; a < 2; a++)
#pragma unroll
    for (int b = 0; b < 2; b++) acc2[a][b] = (f32x4){0.f, 0.f, 0.f, 0.f};
  for (int kc2 = 0; kc2 < 4; kc2++) {
    s8b a0 = *(const s8b*)&wnq_l[((2 * w) * 16 + lm) * 136 + kc2 * 32 + kg * 8];
    s8b a1 = *(const s8b*)&wnq_l[((2 * w + 1) * 16 + lm) * 136 + kc2 * 32 + kg * 8];
    s8b b0 = *(const s8b*)&qc_l[lm * 136 + kc2 * 32 + kg * 8];
    s8b b1 = *(const s8b*)&qc_l[(16 + lm) * 136 + kc2 * 32 + kg * 8];
    acc2[0][0] = __builtin_amdgcn_mfma_f32_16x16x32_bf16(a0, b0, acc2[0][0], 0, 0, 0);
    acc2[0][1] = __builtin_amdgcn_mfma_f32_16x16x32_bf16(a0, b1, acc2[0][1], 0, 0, 0);
    acc2[1][0] = __builtin_amdgcn_mfma_f32_16x16x32_bf16(a1, b0, acc2[1][0], 0, 0, 0);
    acc2[1][1] = __builtin_amdgcn_mfma_f32_16x16x32_bf16(a1, b1, acc2[1][1], 0, 0, 0);
  }
  __syncthreads();   // before overwriting qc_l with projected values

#pragma unroll
  for (int mi = 0; mi < 2; mi++)
#pragma unroll
    for (int nt = 0; nt < 2; nt++)
#pragma unroll
      for (int r = 0; r < 4; r++) {
        int px = nt * 16 + lm;
        int c = (2 * w + mi) * 16 + kg * 4 + r;
        float val = bq_l[c] + rs_l[px] * acc2[mi][nt][r];
        qc_l[px * 136 + c] = f2bf(val);
      }
  __syncthreads();
  const int px0g = y * 128 + x0;
  for (int i = tid; i < 512; i += 256) {
    int px = i >> 4, s16 = i & 15;
    *(s8b*)&qpb[(px0g + px) * 128 + s16 * 8] = *(const s8b*)&qc_l[px * 136 + s16 * 8];
  }
}

// ---------------------------------------------------------------------------
// NATTEN attention, MFMA. One block per 4x4 query cell (grid 1024).
// LDS: q_l[16][136]@0 | k_l[64][136]@4352 (o_l[128][20] f32 reuses this) |
//      v_l[128][72]@21760 | a_l[4][16][72]@40192   total 49408B
// ---------------------------------------------------------------------------
__global__ __launch_bounds__(256, 2) void natten_k2(const unsigned short* __restrict__ qpb,
                                                    const unsigned short* __restrict__ kpb,
                                                    const unsigned short* __restrict__ vb,
                                                    float* __restrict__ out) {
  __shared__ __align__(16) char nsm[49408];
  unsigned short* q_l = (unsigned short*)nsm;
  unsigned short* k_l = (unsigned short*)(nsm + 4352);
  float* o_l = (float*)(nsm + 4352);
  unsigned short* v_l = (unsigned short*)(nsm + 21760);
  unsigned short* a_l = (unsigned short*)(nsm + 40192);

  const int tid = threadIdx.x;
  const int cx = blockIdx.x & 31, cy = blockIdx.x >> 5;
  const int qy0 = cy * 4, qx0 = cx * 4;
  const int ky0 = (cy < 3) ? 0 : ((cy > 28) ? 25 : cy - 3);
  const int kx0 = (cx < 3) ? 0 : ((cx > 28) ? 25 : cx - 3);
  const int w = tid >> 6, lane = tid & 63;
  const int lm = lane & 15, kg = lane >> 4;

  { // q: 16 px x 128c
    int j = tid >> 4, s = tid & 15;
    s8b v = *(const s8b*)&qpb[((qy0 + (j >> 2)) * 128 + qx0 + (j & 3)) * 128 + s * 8];
    *(s8b*)&q_l[j * 136 + s * 8] = v;
  }
  for (int i = tid; i < 1024; i += 256) {  // k keys 0..48, zero 49..63
    int j = i >> 4, s = i & 15;
    s8b v = {0, 0, 0, 0, 0, 0, 0, 0};
    if (j < 49) {
      int ky = j / 7, kx = j - ky * 7;
      v = *(const s8b*)&kpb[((ky0 + ky) * 32 + kx0 + kx) * 128 + s * 8];
    }
    *(s8b*)&k_l[j * 136 + s * 8] = v;
  }
  for (int i = tid; i < 784; i += 256) {   // v transposed [c][key]
    int j = i >> 4, s = i & 15;
    int ky = j / 7, kx = j - ky * 7;
    s8b v = *(const s8b*)&vb[((ky0 + ky) * 32 + kx0 + kx) * 128 + s * 8];
#pragma unroll
    for (int jj = 0; jj < 8; jj++) v_l[(s * 8 + jj) * 72 + j] = (unsigned short)v[jj];
  }
  for (int i = tid; i < 2048; i += 256) {  // zero keys 49..63
    int c = i >> 4, kz = 48 + (i & 15);
    if (kz > 48) v_l[c * 72 + kz] = 0;
  }
  __syncthreads();

  // QK^T, head = wave
  f32x4 lg[4];
  {
    s8b a = *(const s8b*)&q_l[lm * 136 + w * 32 + kg * 8];
#pragma unroll
    for (int nt = 0; nt < 4; nt++) {
      s8b b = *(const s8b*)&k_l[(nt * 16 + lm) * 136 + w * 32 + kg * 8];
      lg[nt] = __builtin_amdgcn_mfma_f32_16x16x32_bf16(a, b, (f32x4){0.f, 0.f, 0.f, 0.f}, 0, 0, 0);
    }
  }
  // masked softmax per row (row q = kg*4+r, cols = keys)
#pragma unroll
  for (int r = 0; r < 4; r++) {
    float l0 = lg[0][r] * SCALE_, l1 = lg[1][r] * SCALE_, l2 = lg[2][r] * SCALE_;
    float l3 = (lm == 0) ? lg[3][r] * SCALE_ : -1e30f;
    float mx = fmaxf(fmaxf(l0, l1), fmaxf(l2, l3));
#pragma unroll
    for (int off = 1; off < 16; off <<= 1) mx = fmaxf(mx, __shfl_xor(mx, off, 64));
    float e0 = __expf(l0 - mx), e1 = __expf(l1 - mx), e2 = __expf(l2 - mx);
    float e3 = (lm == 0) ? __expf(l3 - mx) : 0.f;
    float ss = e0 + e1 + e2 + e3;
#pragma unroll
    for (int off = 1; off < 16; off <<= 1) ss += __shfl_xor(ss, off, 64);
    float inv = 1.f / ss;
    int q = kg * 4 + r;
    a_l[(w * 16 + q) * 72 + lm] = f2bf(e0 * inv);
    a_l[(w * 16 + q) * 72 + 16 + lm] = f2bf(e1 * inv);
    a_l[(w * 16 + q) * 72 + 32 + lm] = f2bf(e2 * inv);
    a_l[(w * 16 + q) * 72 + 48 + lm] = f2bf(e3 * inv);
  }
  __syncthreads();

  // PV with head-averaged A
  f32x4 oacc[2];
  oacc[0] = (f32x4){0.f, 0.f, 0.f, 0.f};
  oacc[1] = (f32x4){0.f, 0.f, 0.f, 0.f};
#pragma unroll
  for (int kc = 0; kc < 2; kc++) {
    int k0 = kc * 32 + kg * 8;
    s8b h0 = *(const s8b*)&a_l[lm * 72 + k0];
    s8b h1 = *(const s8b*)&a_l[(16 + lm) * 72 + k0];
    s8b h2 = *(const s8b*)&a_l[(32 + lm) * 72 + k0];
    s8b h3 = *(const s8b*)&a_l[(48 + lm) * 72 + k0];
    s8b af;
#pragma unroll
    for (int j = 0; j < 8; j++)
      af[j] = (short)f2bf(0.25f * (b2fs(h0[j]) + b2fs(h1[j]) + b2fs(h2[j]) + b2fs(h3[j])));
#pragma unroll
    for (int nt2 = 0; nt2 < 2; nt2++) {
      s8b b = *(const s8b*)&v_l[(w * 32 + nt2 * 16 + lm) * 72 + k0];
      oacc[nt2] = __builtin_amdgcn_mfma_f32_16x16x32_bf16(af, b, oacc[nt2], 0, 0, 0);
    }
  }
  __syncthreads();   // before o_l overwrites k_l region
#pragma unroll
  for (int nt2 = 0; nt2 < 2; nt2++)
#pragma unroll
    for (int r = 0; r < 4; r++)
      o_l[(w * 32 + nt2 * 16 + lm) * 20 + kg * 4 + r] = oacc[nt2][r];
  __syncthreads();
  for (int i = tid; i < 512; i += 256) {
    int c = i >> 2, r = i & 3;
    float4 v = *(const float4*)&o_l[c * 20 + r * 4];
    *(float4*)&out[c * 16384 + (qy0 + r) * 128 + qx0] = v;
  }
}

// ---------------------------------------------------------------------------
extern "C" void kernel_launch(void* const* d_in, const int* in_sizes, int n_in,
                              void* d_out, int out_size, void* d_ws, size_t ws_size,
                              hipStream_t stream) {
  const float* q_in    = (const float*)d_in[0];
  const float* k_in    = (const float*)d_in[1];
  const float* v_in    = (const float*)d_in[2];
  const float* conv_w  = (const float*)d_in[3];
  const float* normq_w = (const float*)d_in[4];
  const float* normk_w = (const float*)d_in[5];
  const float* qproj_w = (const float*)d_in[6];
  const float* qproj_b = (const float*)d_in[7];
  const float* kproj_w = (const float*)d_in[8];
  const float* kproj_b = (const float*)d_in[9];
  float* out = (float*)d_out;

  char* ws = (char*)d_ws;
  unsigned short* qb  = (unsigned short*)(ws);             // [130][130][128] bf16
  unsigned short* qpb = (unsigned short*)(ws + 4326400);   // [16384][128] bf16
  unsigned short* kpb = (unsigned short*)(ws + 8520704);   // [1024][128] bf16
  unsigned short* vb  = (unsigned short*)(ws + 8782848);   // [1024][128] bf16
  unsigned short* wb  = (unsigned short*)(ws + 9044992);   // [9][4][128][40] bf16
  unsigned short* wnq = (unsigned short*)(ws + 9413632);   // [128][136] bf16

  zerob_k<<<dim3(9), 256, 0, stream>>>(qb);
  transpose_k<<<dim3(256), 256, 0, stream>>>(q_in, qb, 16384, 7, 2, 131);
  transpose_k<<<dim3(16), 256, 0, stream>>>(v_in, vb, 1024, 5, 0, 0);
  packw_k<<<dim3(788), 256, 0, stream>>>(conv_w, qproj_w, normq_w, wb, wnq);
  rmsk_k<<<dim3(32), 256, 0, stream>>>(k_in, kproj_w, normk_w, kproj_b, kpb);
  conv_fused_k<<<dim3(512), 256, 0, stream>>>(qb, wb, wnq, qproj_b, qpb);
  natten_k2<<<dim3(1024), 256, 0, stream>>>(qpb, kpb, vb, out);
}

// Round 3
// 135.178 us; speedup vs baseline: 3.0372x; 1.0817x over previous
//
#include <hip/hip_runtime.h>

#define EPS_ 1.1920928955078125e-07f
#define SCALE_ 0.17677669529663687f   // 1/sqrt(32)

typedef __attribute__((ext_vector_type(8))) short s8b;     // 8 bf16 (16B)
typedef __attribute__((ext_vector_type(4))) float f32x4;   // MFMA acc

static __device__ __forceinline__ unsigned short f2bf(float f) {
  unsigned int u = __float_as_uint(f);
  unsigned int r = (u + 0x7fffu + ((u >> 16) & 1u)) >> 16;   // RNE
  return (unsigned short)r;
}
static __device__ __forceinline__ float b2fs(short h) {
  return __uint_as_float(((unsigned int)(unsigned short)h) << 16);
}
static __device__ __forceinline__ int S_(int c) {        // NATTEN window start (cell grid)
  return (c < 3) ? 0 : ((c > 28) ? 25 : (c - 3));
}

// ---------------------------------------------------------------------------
// prep: all packing in one kernel. grid 1001.
//  b in [0,256)     : q fp32 NCHW -> bf16 NHWC into padded qb [130][130][128]
//  b in [256,265)   : zero qb halo border
//  b in [265,281)   : v transpose -> vb [1024][128]
//  b in [281,297)   : k transpose -> kb [1024][128]
//  b in [297,1001)  : weight packs: wb [9][4][128oc][32ic], wnq/wnk [128][128]
// ---------------------------------------------------------------------------
__global__ __launch_bounds__(256) void prep_k(
    const float* __restrict__ q_in, const float* __restrict__ k_in,
    const float* __restrict__ v_in, const float* __restrict__ conv_w,
    const float* __restrict__ normq_w, const float* __restrict__ normk_w,
    const float* __restrict__ qproj_w, const float* __restrict__ kproj_w,
    unsigned short* __restrict__ qb, unsigned short* __restrict__ vb,
    unsigned short* __restrict__ kb, unsigned short* __restrict__ wb,
    unsigned short* __restrict__ wnq, unsigned short* __restrict__ wnk) {
  __shared__ unsigned short t_l[64 * 136];
  const int b = blockIdx.x, tid = threadIdx.x;

  if (b < 256 || (b >= 265 && b < 297)) {
    const float* src;
    unsigned short* dst;
    int N, px0;
    if (b < 256)      { src = q_in; dst = qb; N = 16384; px0 = b * 64; }
    else if (b < 281) { src = v_in; dst = vb; N = 1024;  px0 = (b - 265) * 64; }
    else              { src = k_in; dst = kb; N = 1024;  px0 = (b - 281) * 64; }
    for (int i = tid; i < 2048; i += 256) {
      int c = i >> 4, f = i & 15;
      float4 v = *(const float4*)&src[c * N + px0 + f * 4];
      t_l[(f * 4 + 0) * 136 + c] = f2bf(v.x);
      t_l[(f * 4 + 1) * 136 + c] = f2bf(v.y);
      t_l[(f * 4 + 2) * 136 + c] = f2bf(v.z);
      t_l[(f * 4 + 3) * 136 + c] = f2bf(v.w);
    }
    __syncthreads();
    if (b < 256) {
      for (int i = tid; i < 1024; i += 256) {
        int p = i >> 4, s = i & 15;
        int px = px0 + p;
        int opx = px + 2 * (px >> 7) + 131;   // (y+1)*130 + (x+1)
        *(s8b*)&qb[opx * 128 + s * 8] = *(const s8b*)&t_l[p * 136 + s * 8];
      }
    } else {
      for (int i = tid; i < 1024; i += 256) {
        int p = i >> 4, s = i & 15;
        *(s8b*)&dst[(px0 + p) * 128 + s * 8] = *(const s8b*)&t_l[p * 136 + s * 8];
      }
    }
  } else if (b < 265) {
    int gid = (b - 256) * 256 + tid;   // 2304 threads
    s8b z = {0, 0, 0, 0, 0, 0, 0, 0};
    for (int j = gid; j < 2080; j += 2304) {          // rows 0 and 129
      *(s8b*)&qb[j * 8] = z;
      *(s8b*)&qb[129 * 130 * 128 + j * 8] = z;
    }
    for (int j = gid; j < 2048; j += 2304) {          // cols 0 and 129
      int r = (j >> 4) + 1, s = j & 15;
      *(s8b*)&qb[(r * 130) * 128 + s * 8] = z;
      *(s8b*)&qb[(r * 130 + 129) * 128 + s * 8] = z;
    }
  } else {
    int idx = (b - 297) * 256 + tid;   // < 180224
    if (idx < 147456) {
      int i32 = idx & 31, r = idx >> 5;
      int oc = r & 127, r2 = r >> 7;
      int kc = r2 & 3, t = r2 >> 2;
      wb[idx] = f2bf(conv_w[oc * 1152 + (kc * 32 + i32) * 9 + t]);
    } else if (idx < 163840) {
      int j = idx - 147456;
      wnq[j] = f2bf(qproj_w[j] * normq_w[j & 127]);
    } else {
      int j = idx - 163840;
      wnk[j] = f2bf(kproj_w[j] * normk_w[j & 127]);
    }
  }
}

// ---------------------------------------------------------------------------
// gemm_fused: bx<8 -> k-side rms+proj (128 px each); bx>=8 -> conv3x3 implicit
// GEMM (64 px, M=128 oc, K=1152) + fused rmsnorm + qproj. A-fragments are read
// DIRECTLY from global (L2-hot weights) -> no barriers in the K-loop.
// LDS: in_l @0 (conv [3][66][136]=53856B; kproj [128][136]=34816B; qc_l reuses @0)
//      red @53856 (1024B) | rs @54880 (512B)  total 55392B
// ---------------------------------------------------------------------------
__global__ __launch_bounds__(256, 2) void gemm_fused_k(
    const unsigned short* __restrict__ qb, const unsigned short* __restrict__ wb,
    const unsigned short* __restrict__ wnq, const float* __restrict__ qbias,
    const unsigned short* __restrict__ kb, const unsigned short* __restrict__ wnk,
    const float* __restrict__ kbias, unsigned short* __restrict__ qpb,
    unsigned short* __restrict__ kpb) {
  __shared__ __align__(16) char smem[55392];
  unsigned short* in_l = (unsigned short*)smem;
  unsigned short* qc_l = (unsigned short*)smem;           // reused after barrier
  float* red_l = (float*)(smem + 53856);
  float* rs_l  = (float*)(smem + 54880);

  const int tid = threadIdx.x;
  const int w = tid >> 6, lane = tid & 63;
  const int lm = lane & 15, kg = lane >> 4;

  if (blockIdx.x < 8) {
    // ---------------- k projection ----------------
    const int px0 = blockIdx.x * 128;
    for (int i = tid; i < 2048; i += 256) {
      int px = i >> 4, s = i & 15;
      *(s8b*)&in_l[px * 136 + s * 8] = *(const s8b*)&kb[(px0 + px) * 128 + s * 8];
    }
    __syncthreads();
    {
      int px = tid >> 1, hh = tid & 1;
      float ssum = 0.f;
#pragma unroll
      for (int j = 0; j < 8; j++) {
        s8b v = *(const s8b*)&in_l[px * 136 + hh * 64 + j * 8];
#pragma unroll
        for (int e = 0; e < 8; e++) { float f = b2fs(v[e]); ssum += f * f; }
      }
      red_l[px * 2 + hh] = ssum;
    }
    __syncthreads();
    if (tid < 128)
      rs_l[tid] = rsqrtf((red_l[2 * tid] + red_l[2 * tid + 1]) * (1.f / 128.f) + EPS_);
    __syncthreads();
    f32x4 acc[2][8];
#pragma unroll
    for (int a = 0; a < 2; a++)
#pragma unroll
      for (int n = 0; n < 8; n++) acc[a][n] = (f32x4){0.f, 0.f, 0.f, 0.f};
#pragma unroll
    for (int kc = 0; kc < 4; kc++) {
      s8b a0 = *(const s8b*)&wnk[(2 * w * 16 + lm) * 128 + kc * 32 + kg * 8];
      s8b a1 = *(const s8b*)&wnk[((2 * w + 1) * 16 + lm) * 128 + kc * 32 + kg * 8];
#pragma unroll
      for (int nt = 0; nt < 8; nt++) {
        s8b bf = *(const s8b*)&in_l[(nt * 16 + lm) * 136 + kc * 32 + kg * 8];
        acc[0][nt] = __builtin_amdgcn_mfma_f32_16x16x32_bf16(a0, bf, acc[0][nt], 0, 0, 0);
        acc[1][nt] = __builtin_amdgcn_mfma_f32_16x16x32_bf16(a1, bf, acc[1][nt], 0, 0, 0);
      }
    }
    __syncthreads();
#pragma unroll
    for (int mi = 0; mi < 2; mi++)
#pragma unroll
      for (int nt = 0; nt < 8; nt++)
#pragma unroll
        for (int r = 0; r < 4; r++) {
          int px = nt * 16 + lm, c = (2 * w + mi) * 16 + kg * 4 + r;
          in_l[px * 136 + c] = f2bf(kbias[c] + rs_l[px] * acc[mi][nt][r]);
        }
    __syncthreads();
    for (int i = tid; i < 2048; i += 256) {
      int px = i >> 4, s = i & 15;
      *(s8b*)&kpb[(px0 + px) * 128 + s * 8] = *(const s8b*)&in_l[px * 136 + s * 8];
    }
    return;
  }

  // ---------------- conv + rms + qproj ----------------
  const int bx = blockIdx.x - 8;
  const int y = bx >> 1, x0 = (bx & 1) * 64;

  for (int i = tid; i < 3168; i += 256) {         // [3][66][136] halo tile
    int s = i & 15, r = i >> 4;
    int ry = r / 66, lx = r - ry * 66;
    *(s8b*)&in_l[(ry * 66 + lx) * 136 + s * 8] =
        *(const s8b*)&qb[((y + ry) * 130 + x0 + lx) * 128 + s * 8];
  }
  __syncthreads();

  f32x4 acc[2][4];
#pragma unroll
  for (int a = 0; a < 2; a++)
#pragma unroll
    for (int n = 0; n < 4; n++) acc[a][n] = (f32x4){0.f, 0.f, 0.f, 0.f};

#pragma unroll
  for (int t = 0; t < 9; t++) {
    const int dy = t / 3, dx = t - (t / 3) * 3;
#pragma unroll
    for (int kc = 0; kc < 4; kc++) {
      const unsigned short* wp = wb + (t * 4 + kc) * 4096;
      s8b a0 = *(const s8b*)&wp[(2 * w * 16 + lm) * 32 + kg * 8];
      s8b a1 = *(const s8b*)&wp[((2 * w + 1) * 16 + lm) * 32 + kg * 8];
      const int ic0 = kc * 32;
#pragma unroll
      for (int nt = 0; nt < 4; nt++) {
        s8b bf = *(const s8b*)&in_l[(dy * 66 + nt * 16 + lm + dx) * 136 + ic0 + kg * 8];
        acc[0][nt] = __builtin_amdgcn_mfma_f32_16x16x32_bf16(a0, bf, acc[0][nt], 0, 0, 0);
        acc[1][nt] = __builtin_amdgcn_mfma_f32_16x16x32_bf16(a1, bf, acc[1][nt], 0, 0, 0);
      }
    }
  }
  __syncthreads();   // in_l reads done; qc_l reuses the same region
#pragma unroll
  for (int mi = 0; mi < 2; mi++)
#pragma unroll
    for (int nt = 0; nt < 4; nt++)
#pragma unroll
      for (int r = 0; r < 4; r++) {
        int px = nt * 16 + lm, c = (2 * w + mi) * 16 + kg * 4 + r;
        qc_l[px * 136 + c] = f2bf(acc[mi][nt][r]);
      }
  __syncthreads();
  {
    int px = tid >> 2, t4 = tid & 3;
    float ssum = 0.f;
#pragma unroll
    for (int j = 0; j < 4; j++) {
      s8b v = *(const s8b*)&qc_l[px * 136 + t4 * 32 + j * 8];
#pragma unroll
      for (int e = 0; e < 8; e++) { float f = b2fs(v[e]); ssum += f * f; }
    }
    red_l[px * 4 + t4] = ssum;
  }
  __syncthreads();
  if (tid < 64)
    rs_l[tid] = rsqrtf((red_l[4 * tid] + red_l[4 * tid + 1] + red_l[4 * tid + 2] +
                        red_l[4 * tid + 3]) * (1.f / 128.f) + EPS_);
  __syncthreads();

  f32x4 acc2[2][4];
#pragma unroll
  for (int a = 0; a < 2; a++)
#pragma unroll
    for (int n = 0; n < 4; n++) acc2[a][n] = (f32x4){0.f, 0.f, 0.f, 0.f};
#pragma unroll
  for (int kc = 0; kc < 4; kc++) {
    s8b a0 = *(const s8b*)&wnq[(2 * w * 16 + lm) * 128 + kc * 32 + kg * 8];
    s8b a1 = *(const s8b*)&wnq[((2 * w + 1) * 16 + lm) * 128 + kc * 32 + kg * 8];
#pragma unroll
    for (int nt = 0; nt < 4; nt++) {
      s8b bf = *(const s8b*)&qc_l[(nt * 16 + lm) * 136 + kc * 32 + kg * 8];
      acc2[0][nt] = __builtin_amdgcn_mfma_f32_16x16x32_bf16(a0, bf, acc2[0][nt], 0, 0, 0);
      acc2[1][nt] = __builtin_amdgcn_mfma_f32_16x16x32_bf16(a1, bf, acc2[1][nt], 0, 0, 0);
    }
  }
  __syncthreads();
#pragma unroll
  for (int mi = 0; mi < 2; mi++)
#pragma unroll
    for (int nt = 0; nt < 4; nt++)
#pragma unroll
      for (int r = 0; r < 4; r++) {
        int px = nt * 16 + lm, c = (2 * w + mi) * 16 + kg * 4 + r;
        qc_l[px * 136 + c] = f2bf(qbias[c] + rs_l[px] * acc2[mi][nt][r]);
      }
  __syncthreads();
  const int pg0 = y * 128 + x0;
  for (int i = tid; i < 1024; i += 256) {
    int px = i >> 4, s = i & 15;
    *(s8b*)&qpb[(pg0 + px) * 128 + s * 8] = *(const s8b*)&qc_l[px * 136 + s * 8];
  }
}

// ---------------------------------------------------------------------------
// natten: one block per 2x2 cells = 8x8 queries sharing an 8x8 key window.
// Q/K fragments straight from global (L2-hot); per-query 49-of-64 mask in
// softmax; head-mean via LDS f32 atomics into pa_l; PV = 16 MFMA per wave.
// LDS: v_l[128][72] @0 (18432B) | pa_l[64][69] f32 @18432 (17664B)
//      o_l[128][68] f32 @0 (34816B, reused)          total 36096B
// ---------------------------------------------------------------------------
__global__ __launch_bounds__(256, 2) void natten_k3(
    const unsigned short* __restrict__ qpb, const unsigned short* __restrict__ kpb,
    const unsigned short* __restrict__ vb, float* __restrict__ out) {
  __shared__ __align__(16) char nsm[36096];
  unsigned short* v_l = (unsigned short*)nsm;
  float* pa_l = (float*)(nsm + 18432);
  float* o_l = (float*)nsm;

  const int tid = threadIdx.x;
  const int CY = blockIdx.x >> 4, CX = blockIdx.x & 15;
  const int w = tid >> 6, lane = tid & 63;
  const int lm = lane & 15, kg = lane >> 4;

  const int sy0 = S_(2 * CY), sy1 = S_(2 * CY + 1);
  const int sx0 = S_(2 * CX), sx1 = S_(2 * CX + 1);
  const int kyb = min(sy0, 24), kxb = min(sx0, 24);
  const int oy0 = sy0 - kyb, oy1 = sy1 - kyb;     // in {0,1}
  const int ox0 = sx0 - kxb, ox1 = sx1 - kxb;

  // stage v transposed: v_l[c][key]
  for (int i = tid; i < 1024; i += 256) {
    int j = i >> 4, s = i & 15;
    int ky = j >> 3, kx = j & 7;
    s8b v = *(const s8b*)&vb[((kyb + ky) * 32 + kxb + kx) * 128 + s * 8];
#pragma unroll
    for (int e = 0; e < 8; e++) v_l[(s * 8 + e) * 72 + j] = (unsigned short)v[e];
  }
  for (int i = tid; i < 4416; i += 256) pa_l[i] = 0.f;

  // QK^T (head = wave), fragments from global
  const int h = w;
  f32x4 lg[4][4];
  {
    s8b af[4], bf[4];
#pragma unroll
    for (int mt = 0; mt < 4; mt++) {
      int j = mt * 16 + lm;
      int qy = j >> 3, qx = j & 7;
      af[mt] = *(const s8b*)&qpb[((CY * 8 + qy) * 128 + CX * 8 + qx) * 128 + h * 32 + kg * 8];
    }
#pragma unroll
    for (int nt = 0; nt < 4; nt++) {
      int n = nt * 16 + lm;
      int ky = n >> 3, kx = n & 7;
      bf[nt] = *(const s8b*)&kpb[((kyb + ky) * 32 + kxb + kx) * 128 + h * 32 + kg * 8];
    }
#pragma unroll
    for (int mt = 0; mt < 4; mt++)
#pragma unroll
      for (int nt = 0; nt < 4; nt++)
        lg[mt][nt] = __builtin_amdgcn_mfma_f32_16x16x32_bf16(
            af[mt], bf[nt], (f32x4){0.f, 0.f, 0.f, 0.f}, 0, 0, 0);
  }
  __syncthreads();   // v_l staged + pa_l zeroed

  // masked softmax, head-averaged accumulate into pa_l
  const int kyA = lm >> 3, kxq = lm & 7;
  const bool kxv0 = (unsigned)(kxq - ox0) < 7u;
  const bool kxv1 = (unsigned)(kxq - ox1) < 7u;
#pragma unroll
  for (int mt = 0; mt < 4; mt++) {
#pragma unroll
    for (int r = 0; r < 4; r++) {
      int j = mt * 16 + kg * 4 + r;
      int oy = ((j >> 5) & 1) ? oy1 : oy0;
      bool kxv = ((j >> 2) & 1) ? kxv1 : kxv0;
      float l[4];
#pragma unroll
      for (int nt = 0; nt < 4; nt++) {
        int ky = 2 * nt + kyA;
        bool valid = kxv && ((unsigned)(ky - oy) < 7u);
        l[nt] = valid ? lg[mt][nt][r] * SCALE_ : -1e30f;
      }
      float mx = fmaxf(fmaxf(l[0], l[1]), fmaxf(l[2], l[3]));
#pragma unroll
      for (int off = 1; off < 16; off <<= 1) mx = fmaxf(mx, __shfl_xor(mx, off, 64));
      float e0 = __expf(l[0] - mx), e1 = __expf(l[1] - mx);
      float e2 = __expf(l[2] - mx), e3 = __expf(l[3] - mx);
      float ss = e0 + e1 + e2 + e3;
#pragma unroll
      for (int off = 1; off < 16; off <<= 1) ss += __shfl_xor(ss, off, 64);
      float inv = 0.25f / ss;
      atomicAdd(&pa_l[j * 69 + lm], e0 * inv);
      atomicAdd(&pa_l[j * 69 + 16 + lm], e1 * inv);
      atomicAdd(&pa_l[j * 69 + 32 + lm], e2 * inv);
      atomicAdd(&pa_l[j * 69 + 48 + lm], e3 * inv);
    }
  }
  __syncthreads();

  // PV: O = P̄·V ; wave covers c-band w*32
  f32x4 oacc[4][2];
#pragma unroll
  for (int a = 0; a < 4; a++)
#pragma unroll
    for (int n = 0; n < 2; n++) oacc[a][n] = (f32x4){0.f, 0.f, 0.f, 0.f};
#pragma unroll
  for (int mt = 0; mt < 4; mt++) {
#pragma unroll
    for (int kc = 0; kc < 2; kc++) {
      s8b afr;
#pragma unroll
      for (int e = 0; e < 8; e++)
        afr[e] = (short)f2bf(pa_l[(mt * 16 + lm) * 69 + kc * 32 + kg * 8 + e]);
#pragma unroll
      for (int nt2 = 0; nt2 < 2; nt2++) {
        s8b bfr = *(const s8b*)&v_l[(w * 32 + nt2 * 16 + lm) * 72 + kc * 32 + kg * 8];
        oacc[mt][nt2] = __builtin_amdgcn_mfma_f32_16x16x32_bf16(afr, bfr, oacc[mt][nt2], 0, 0, 0);
      }
    }
  }
  __syncthreads();   // all v_l / pa_l reads done before o_l overwrite
#pragma unroll
  for (int mt = 0; mt < 4; mt++)
#pragma unroll
    for (int nt2 = 0; nt2 < 2; nt2++)
#pragma unroll
      for (int r = 0; r < 4; r++)
        o_l[(w * 32 + nt2 * 16 + lm) * 68 + mt * 16 + kg * 4 + r] = oacc[mt][nt2][r];
  __syncthreads();
  for (int i = tid; i < 1024; i += 256) {
    int c = i >> 3, qy = i & 7;
    float4 v0 = *(const float4*)&o_l[c * 68 + qy * 8];
    float4 v1 = *(const float4*)&o_l[c * 68 + qy * 8 + 4];
    float* op = &out[c * 16384 + (CY * 8 + qy) * 128 + CX * 8];
    *(float4*)op = v0;
    *(float4*)(op + 4) = v1;
  }
}

// ---------------------------------------------------------------------------
extern "C" void kernel_launch(void* const* d_in, const int* in_sizes, int n_in,
                              void* d_out, int out_size, void* d_ws, size_t ws_size,
                              hipStream_t stream) {
  const float* q_in    = (const float*)d_in[0];
  const float* k_in    = (const float*)d_in[1];
  const float* v_in    = (const float*)d_in[2];
  const float* conv_w  = (const float*)d_in[3];
  const float* normq_w = (const float*)d_in[4];
  const float* normk_w = (const float*)d_in[5];
  const float* qproj_w = (const float*)d_in[6];
  const float* qproj_b = (const float*)d_in[7];
  const float* kproj_w = (const float*)d_in[8];
  const float* kproj_b = (const float*)d_in[9];
  float* out = (float*)d_out;

  char* ws = (char*)d_ws;
  unsigned short* qb  = (unsigned short*)(ws);             // [130][130][128]
  unsigned short* qpb = (unsigned short*)(ws + 4326400);   // [16384][128]
  unsigned short* kpb = (unsigned short*)(ws + 8520704);   // [1024][128]
  unsigned short* vb  = (unsigned short*)(ws + 8782848);   // [1024][128]
  unsigned short* kb  = (unsigned short*)(ws + 9044992);   // [1024][128]
  unsigned short* wb  = (unsigned short*)(ws + 9307136);   // [9][4][128][32]
  unsigned short* wnq = (unsigned short*)(ws + 9602048);   // [128][128]
  unsigned short* wnk = (unsigned short*)(ws + 9634816);   // [128][128]

  prep_k<<<dim3(1001), 256, 0, stream>>>(q_in, k_in, v_in, conv_w, normq_w, normk_w,
                                         qproj_w, kproj_w, qb, vb, kb, wb, wnq, wnk);
  gemm_fused_k<<<dim3(264), 256, 0, stream>>>(qb, wb, wnq, qproj_b, kb, wnk, kproj_b,
                                              qpb, kpb);
  natten_k3<<<dim3(256), 256, 0, stream>>>(qpb, kpb, vb, out);
}

// Round 4
// 112.957 us; speedup vs baseline: 3.6346x; 1.1967x over previous
//
#include <hip/hip_runtime.h>

#define EPS_ 1.1920928955078125e-07f
#define SCALE_ 0.17677669529663687f   // 1/sqrt(32)

typedef __attribute__((ext_vector_type(8))) short s8b;     // 8 bf16 (16B)
typedef __attribute__((ext_vector_type(4))) float f32x4;   // MFMA acc

static __device__ __forceinline__ unsigned short f2bf(float f) {
  unsigned int u = __float_as_uint(f);
  unsigned int r = (u + 0x7fffu + ((u >> 16) & 1u)) >> 16;   // RNE
  return (unsigned short)r;
}
static __device__ __forceinline__ float b2fs(short h) {
  return __uint_as_float(((unsigned int)(unsigned short)h) << 16);
}
static __device__ __forceinline__ int S_(int c) {        // NATTEN window start (cell grid)
  return (c < 3) ? 0 : ((c > 28) ? 25 : (c - 3));
}

// ---------------------------------------------------------------------------
// prep: packing + full k-side rms+proj. grid 937.
//  [0,256)   q fp32 NCHW -> bf16 NHWC padded qb [130][130][128]
//  [256,265) zero qb halo border
//  [265,281) v -> vb [1024][128] bf16 NHWC
//  [281,297) k-side: rms(bf16 stage) + kproj MFMA -> kpb [1024][128] (64 px/blk)
//  [297,937) weight packs: wb [9][4][128oc][32ic], wnq [128][128]
// ---------------------------------------------------------------------------
__global__ __launch_bounds__(256) void prep_k(
    const float* __restrict__ q_in, const float* __restrict__ k_in,
    const float* __restrict__ v_in, const float* __restrict__ conv_w,
    const float* __restrict__ normq_w, const float* __restrict__ normk_w,
    const float* __restrict__ qproj_w, const float* __restrict__ kproj_w,
    const float* __restrict__ kbias,
    unsigned short* __restrict__ qb, unsigned short* __restrict__ vb,
    unsigned short* __restrict__ kpb, unsigned short* __restrict__ wb,
    unsigned short* __restrict__ wnq) {
  __shared__ __align__(16) char smem[53504];
  unsigned short* t_l = (unsigned short*)smem;            // [64][136]
  unsigned short* x_l = (unsigned short*)smem;            // [64][136] (k-proj)
  unsigned short* wnk_l = (unsigned short*)(smem + 17408);// [128][136]
  float* red_l = (float*)(smem + 52224);                  // [256]
  float* rs_l  = (float*)(smem + 53248);                  // [64]
  const int b = blockIdx.x, tid = threadIdx.x;
  const int w = tid >> 6, lane = tid & 63;
  const int lm = lane & 15, kg = lane >> 4;

  if (b < 256 || (b >= 265 && b < 281)) {
    const float* src = (b < 256) ? q_in : v_in;
    const int N = (b < 256) ? 16384 : 1024;
    const int px0 = (b < 256) ? b * 64 : (b - 265) * 64;
    for (int i = tid; i < 2048; i += 256) {
      int c = i >> 4, f = i & 15;
      float4 v = *(const float4*)&src[c * N + px0 + f * 4];
      t_l[(f * 4 + 0) * 136 + c] = f2bf(v.x);
      t_l[(f * 4 + 1) * 136 + c] = f2bf(v.y);
      t_l[(f * 4 + 2) * 136 + c] = f2bf(v.z);
      t_l[(f * 4 + 3) * 136 + c] = f2bf(v.w);
    }
    __syncthreads();
    if (b < 256) {
      for (int i = tid; i < 1024; i += 256) {
        int p = i >> 4, s = i & 15;
        int px = px0 + p;
        int opx = px + 2 * (px >> 7) + 131;   // (y+1)*130 + (x+1)
        *(s8b*)&qb[opx * 128 + s * 8] = *(const s8b*)&t_l[p * 136 + s * 8];
      }
    } else {
      for (int i = tid; i < 1024; i += 256) {
        int p = i >> 4, s = i & 15;
        *(s8b*)&vb[(px0 + p) * 128 + s * 8] = *(const s8b*)&t_l[p * 136 + s * 8];
      }
    }
  } else if (b < 265) {
    int gid = (b - 256) * 256 + tid;   // 2304 threads
    s8b z = {0, 0, 0, 0, 0, 0, 0, 0};
    for (int j = gid; j < 2080; j += 2304) {
      *(s8b*)&qb[j * 8] = z;
      *(s8b*)&qb[129 * 130 * 128 + j * 8] = z;
    }
    for (int j = gid; j < 2048; j += 2304) {
      int r = (j >> 4) + 1, s = j & 15;
      *(s8b*)&qb[(r * 130) * 128 + s * 8] = z;
      *(s8b*)&qb[(r * 130 + 129) * 128 + s * 8] = z;
    }
  } else if (b < 297) {
    // ------- k-side rms + proj, 64 px -------
    const int px0 = (b - 281) * 64;
    for (int i = tid; i < 2048; i += 256) {   // stage k transposed bf16
      int c = i >> 4, f = i & 15;
      float4 v = *(const float4*)&k_in[c * 1024 + px0 + f * 4];
      x_l[(f * 4 + 0) * 136 + c] = f2bf(v.x);
      x_l[(f * 4 + 1) * 136 + c] = f2bf(v.y);
      x_l[(f * 4 + 2) * 136 + c] = f2bf(v.z);
      x_l[(f * 4 + 3) * 136 + c] = f2bf(v.w);
    }
    for (int i = tid; i < 16384; i += 256) {  // wnk = kproj_w * normk
      int o = i >> 7, c = i & 127;
      wnk_l[o * 136 + c] = f2bf(kproj_w[i] * normk_w[c]);
    }
    __syncthreads();
    {
      int px = tid >> 2, t4 = tid & 3;
      float ssum = 0.f;
#pragma unroll
      for (int j = 0; j < 4; j++) {
        s8b v = *(const s8b*)&x_l[px * 136 + t4 * 32 + j * 8];
#pragma unroll
        for (int e = 0; e < 8; e++) { float f = b2fs(v[e]); ssum += f * f; }
      }
      red_l[px * 4 + t4] = ssum;
    }
    __syncthreads();
    if (tid < 64)
      rs_l[tid] = rsqrtf((red_l[4 * tid] + red_l[4 * tid + 1] + red_l[4 * tid + 2] +
                          red_l[4 * tid + 3]) * (1.f / 128.f) + EPS_);
    __syncthreads();
    f32x4 acc[2][4];
#pragma unroll
    for (int a = 0; a < 2; a++)
#pragma unroll
      for (int n = 0; n < 4; n++) acc[a][n] = (f32x4){0.f, 0.f, 0.f, 0.f};
#pragma unroll
    for (int kc = 0; kc < 4; kc++) {
      s8b a0 = *(const s8b*)&wnk_l[(2 * w * 16 + lm) * 136 + kc * 32 + kg * 8];
      s8b a1 = *(const s8b*)&wnk_l[((2 * w + 1) * 16 + lm) * 136 + kc * 32 + kg * 8];
#pragma unroll
      for (int nt = 0; nt < 4; nt++) {
        s8b bf = *(const s8b*)&x_l[(nt * 16 + lm) * 136 + kc * 32 + kg * 8];
        acc[0][nt] = __builtin_amdgcn_mfma_f32_16x16x32_bf16(a0, bf, acc[0][nt], 0, 0, 0);
        acc[1][nt] = __builtin_amdgcn_mfma_f32_16x16x32_bf16(a1, bf, acc[1][nt], 0, 0, 0);
      }
    }
    __syncthreads();
#pragma unroll
    for (int mi = 0; mi < 2; mi++)
#pragma unroll
      for (int nt = 0; nt < 4; nt++)
#pragma unroll
        for (int r = 0; r < 4; r++) {
          int px = nt * 16 + lm, c = (2 * w + mi) * 16 + kg * 4 + r;
          x_l[px * 136 + c] = f2bf(kbias[c] + rs_l[px] * acc[mi][nt][r]);
        }
    __syncthreads();
    for (int i = tid; i < 1024; i += 256) {
      int px = i >> 4, s = i & 15;
      *(s8b*)&kpb[(px0 + px) * 128 + s * 8] = *(const s8b*)&x_l[px * 136 + s * 8];
    }
  } else {
    int idx = (b - 297) * 256 + tid;   // < 163840
    if (idx < 147456) {
      int i32 = idx & 31, r = idx >> 5;
      int oc = r & 127, r2 = r >> 7;
      int kc = r2 & 3, t = r2 >> 2;
      wb[idx] = f2bf(conv_w[oc * 1152 + (kc * 32 + i32) * 9 + t]);
    } else {
      int j = idx - 147456;
      wnq[j] = f2bf(qproj_w[j] * normq_w[j & 127]);
    }
  }
}

// ---------------------------------------------------------------------------
// fused: conv3x3 (implicit GEMM) + rms + qproj + NATTEN attention + output.
// One block per 8x8 output tile (grid 256). Weights (wb/wnq) read straight
// from global (L2-hot). LDS phase-reuse:
//  region0 @0 (34816B): in_l [10][12][136] -> qc_l/qpx [64][136] -> a_l[4][64][68]
//                       -> o_l [128][68] f32
//  region1 @34816 (18432B): v_l [128][72] bf16 (transposed)
//  red @53248 (1024) | rs @54272 (256)   total 54528B
// ---------------------------------------------------------------------------
__global__ __launch_bounds__(256) void fused_k(
    const unsigned short* __restrict__ qb, const unsigned short* __restrict__ wb,
    const unsigned short* __restrict__ wnq, const float* __restrict__ qbias,
    const unsigned short* __restrict__ kpb, const unsigned short* __restrict__ vb,
    float* __restrict__ out) {
  __shared__ __align__(16) char smem[54528];
  unsigned short* in_l = (unsigned short*)smem;
  unsigned short* qc_l = (unsigned short*)smem;
  unsigned short* a_l  = (unsigned short*)smem;
  float* o_l = (float*)smem;
  unsigned short* v_l = (unsigned short*)(smem + 34816);
  float* red_l = (float*)(smem + 53248);
  float* rs_l  = (float*)(smem + 54272);

  const int tid = threadIdx.x;
  const int CY = blockIdx.x >> 4, CX = blockIdx.x & 15;
  const int Y0 = CY * 8, X0 = CX * 8;
  const int w = tid >> 6, lane = tid & 63;
  const int lm = lane & 15, kg = lane >> 4;

  const int sy0 = S_(2 * CY), sy1 = S_(2 * CY + 1);
  const int sx0 = S_(2 * CX), sx1 = S_(2 * CX + 1);
  const int kyb = min(sy0, 24), kxb = min(sx0, 24);
  const int oy0 = sy0 - kyb, oy1 = sy1 - kyb;
  const int ox0 = sx0 - kxb, ox1 = sx1 - kxb;

  // stage conv halo [10][12(pad)][136] + v window transposed
  for (int i = tid; i < 1600; i += 256) {
    int s = i & 15, r = i >> 4;
    int ry = r / 10, rx = r - ry * 10;
    *(s8b*)&in_l[(ry * 12 + rx) * 136 + s * 8] =
        *(const s8b*)&qb[((Y0 + ry) * 130 + X0 + rx) * 128 + s * 8];
  }
  for (int i = tid; i < 1024; i += 256) {
    int j = i >> 4, s = i & 15;
    int ky = j >> 3, kx = j & 7;
    s8b v = *(const s8b*)&vb[((kyb + ky) * 32 + kxb + kx) * 128 + s * 8];
#pragma unroll
    for (int e = 0; e < 8; e++) v_l[(s * 8 + e) * 72 + j] = (unsigned short)v[e];
  }
  __syncthreads();

  // ---- conv implicit GEMM: M=128 oc, N=64 px, K=1152 ----
  f32x4 acc[2][4];
#pragma unroll
  for (int a = 0; a < 2; a++)
#pragma unroll
    for (int n = 0; n < 4; n++) acc[a][n] = (f32x4){0.f, 0.f, 0.f, 0.f};
#pragma unroll
  for (int t = 0; t < 9; t++) {
    const int dy = t / 3, dx = t - (t / 3) * 3;
#pragma unroll
    for (int kc = 0; kc < 4; kc++) {
      const unsigned short* wp = wb + (t * 4 + kc) * 4096;
      s8b a0 = *(const s8b*)&wp[(2 * w * 16 + lm) * 32 + kg * 8];
      s8b a1 = *(const s8b*)&wp[((2 * w + 1) * 16 + lm) * 32 + kg * 8];
#pragma unroll
      for (int nt = 0; nt < 4; nt++) {
        int qy = 2 * nt + (lm >> 3), qx = lm & 7;
        s8b bf = *(const s8b*)&in_l[((qy + dy) * 12 + qx + dx) * 136 + kc * 32 + kg * 8];
        acc[0][nt] = __builtin_amdgcn_mfma_f32_16x16x32_bf16(a0, bf, acc[0][nt], 0, 0, 0);
        acc[1][nt] = __builtin_amdgcn_mfma_f32_16x16x32_bf16(a1, bf, acc[1][nt], 0, 0, 0);
      }
    }
  }
  __syncthreads();
#pragma unroll
  for (int mi = 0; mi < 2; mi++)
#pragma unroll
    for (int nt = 0; nt < 4; nt++)
#pragma unroll
      for (int r = 0; r < 4; r++) {
        int px = nt * 16 + lm, c = (2 * w + mi) * 16 + kg * 4 + r;
        qc_l[px * 136 + c] = f2bf(acc[mi][nt][r]);
      }
  __syncthreads();

  // ---- rms over channels ----
  {
    int px = tid >> 2, t4 = tid & 3;
    float ssum = 0.f;
#pragma unroll
    for (int j = 0; j < 4; j++) {
      s8b v = *(const s8b*)&qc_l[px * 136 + t4 * 32 + j * 8];
#pragma unroll
      for (int e = 0; e < 8; e++) { float f = b2fs(v[e]); ssum += f * f; }
    }
    red_l[px * 4 + t4] = ssum;
  }
  __syncthreads();
  if (tid < 64)
    rs_l[tid] = rsqrtf((red_l[4 * tid] + red_l[4 * tid + 1] + red_l[4 * tid + 2] +
                        red_l[4 * tid + 3]) * (1.f / 128.f) + EPS_);
  __syncthreads();

  // ---- qproj ----
  f32x4 acc2[2][4];
#pragma unroll
  for (int a = 0; a < 2; a++)
#pragma unroll
    for (int n = 0; n < 4; n++) acc2[a][n] = (f32x4){0.f, 0.f, 0.f, 0.f};
#pragma unroll
  for (int kc = 0; kc < 4; kc++) {
    s8b a0 = *(const s8b*)&wnq[(2 * w * 16 + lm) * 128 + kc * 32 + kg * 8];
    s8b a1 = *(const s8b*)&wnq[((2 * w + 1) * 16 + lm) * 128 + kc * 32 + kg * 8];
#pragma unroll
    for (int nt = 0; nt < 4; nt++) {
      s8b bf = *(const s8b*)&qc_l[(nt * 16 + lm) * 136 + kc * 32 + kg * 8];
      acc2[0][nt] = __builtin_amdgcn_mfma_f32_16x16x32_bf16(a0, bf, acc2[0][nt], 0, 0, 0);
      acc2[1][nt] = __builtin_amdgcn_mfma_f32_16x16x32_bf16(a1, bf, acc2[1][nt], 0, 0, 0);
    }
  }
  __syncthreads();
#pragma unroll
  for (int mi = 0; mi < 2; mi++)
#pragma unroll
    for (int nt = 0; nt < 4; nt++)
#pragma unroll
      for (int r = 0; r < 4; r++) {
        int px = nt * 16 + lm, c = (2 * w + mi) * 16 + kg * 4 + r;
        qc_l[px * 136 + c] = f2bf(qbias[c] + rs_l[px] * acc2[mi][nt][r]);
      }
  __syncthreads();

  // ---- QK^T (head = wave), B from global kpb ----
  const int h = w;
  f32x4 lg[4][4];
  {
    s8b af[4], bf[4];
#pragma unroll
    for (int mt = 0; mt < 4; mt++)
      af[mt] = *(const s8b*)&qc_l[(mt * 16 + lm) * 136 + h * 32 + kg * 8];
#pragma unroll
    for (int nt = 0; nt < 4; nt++) {
      int n = nt * 16 + lm;
      int ky = n >> 3, kx = n & 7;
      bf[nt] = *(const s8b*)&kpb[((kyb + ky) * 32 + kxb + kx) * 128 + h * 32 + kg * 8];
    }
#pragma unroll
    for (int mt = 0; mt < 4; mt++)
#pragma unroll
      for (int nt = 0; nt < 4; nt++)
        lg[mt][nt] = __builtin_amdgcn_mfma_f32_16x16x32_bf16(
            af[mt], bf[nt], (f32x4){0.f, 0.f, 0.f, 0.f}, 0, 0, 0);
  }
  __syncthreads();   // qpx reads done; a_l overwrites region0

  // ---- masked softmax (per head), store P_h bf16 ----
  const int kyA = lm >> 3, kxq = lm & 7;
  const bool kxv0 = (unsigned)(kxq - ox0) < 7u;
  const bool kxv1 = (unsigned)(kxq - ox1) < 7u;
#pragma unroll
  for (int mt = 0; mt < 4; mt++) {
#pragma unroll
    for (int r = 0; r < 4; r++) {
      int j = mt * 16 + kg * 4 + r;
      int oy = ((j >> 5) & 1) ? oy1 : oy0;
      bool kxv = ((j >> 2) & 1) ? kxv1 : kxv0;
      float l[4];
#pragma unroll
      for (int nt = 0; nt < 4; nt++) {
        int ky = 2 * nt + kyA;
        bool valid = kxv && ((unsigned)(ky - oy) < 7u);
        l[nt] = valid ? lg[mt][nt][r] * SCALE_ : -1e30f;
      }
      float mx = fmaxf(fmaxf(l[0], l[1]), fmaxf(l[2], l[3]));
#pragma unroll
      for (int off = 1; off < 16; off <<= 1) mx = fmaxf(mx, __shfl_xor(mx, off, 64));
      float e0 = __expf(l[0] - mx), e1 = __expf(l[1] - mx);
      float e2 = __expf(l[2] - mx), e3 = __expf(l[3] - mx);
      float ss = e0 + e1 + e2 + e3;
#pragma unroll
      for (int off = 1; off < 16; off <<= 1) ss += __shfl_xor(ss, off, 64);
      float inv = 1.f / ss;
      unsigned short* ap = &a_l[(h * 64 + j) * 68];
      ap[lm] = f2bf(e0 * inv);
      ap[16 + lm] = f2bf(e1 * inv);
      ap[32 + lm] = f2bf(e2 * inv);
      ap[48 + lm] = f2bf(e3 * inv);
    }
  }
  __syncthreads();

  // ---- PV: O = 0.25 * sum_h P_h · V ; wave covers c-band w*32 ----
  f32x4 oacc[4][2];
#pragma unroll
  for (int a = 0; a < 4; a++)
#pragma unroll
    for (int n = 0; n < 2; n++) oacc[a][n] = (f32x4){0.f, 0.f, 0.f, 0.f};
#pragma unroll
  for (int kc = 0; kc < 2; kc++) {
    s8b bfr[2];
#pragma unroll
    for (int nt2 = 0; nt2 < 2; nt2++)
      bfr[nt2] = *(const s8b*)&v_l[(w * 32 + nt2 * 16 + lm) * 72 + kc * 32 + kg * 8];
#pragma unroll
    for (int hh = 0; hh < 4; hh++) {
#pragma unroll
      for (int mt = 0; mt < 4; mt++) {
        s8b afr = *(const s8b*)&a_l[(hh * 64 + mt * 16 + lm) * 68 + kc * 32 + kg * 8];
#pragma unroll
        for (int nt2 = 0; nt2 < 2; nt2++)
          oacc[mt][nt2] = __builtin_amdgcn_mfma_f32_16x16x32_bf16(afr, bfr[nt2], oacc[mt][nt2], 0, 0, 0);
      }
    }
  }
  __syncthreads();   // a_l reads done before o_l overwrite
#pragma unroll
  for (int mt = 0; mt < 4; mt++)
#pragma unroll
    for (int nt2 = 0; nt2 < 2; nt2++)
#pragma unroll
      for (int r = 0; r < 4; r++)
        o_l[(w * 32 + nt2 * 16 + lm) * 68 + mt * 16 + kg * 4 + r] = 0.25f * oacc[mt][nt2][r];
  __syncthreads();
  for (int i = tid; i < 2048; i += 256) {
    int c = i >> 4, rr = i & 15;
    int qy = rr >> 1, hx = rr & 1;
    float4 v = *(const float4*)&o_l[c * 68 + qy * 8 + hx * 4];
    *(float4*)&out[c * 16384 + (Y0 + qy) * 128 + X0 + hx * 4] = v;
  }
}

// ---------------------------------------------------------------------------
extern "C" void kernel_launch(void* const* d_in, const int* in_sizes, int n_in,
                              void* d_out, int out_size, void* d_ws, size_t ws_size,
                              hipStream_t stream) {
  const float* q_in    = (const float*)d_in[0];
  const float* k_in    = (const float*)d_in[1];
  const float* v_in    = (const float*)d_in[2];
  const float* conv_w  = (const float*)d_in[3];
  const float* normq_w = (const float*)d_in[4];
  const float* normk_w = (const float*)d_in[5];
  const float* qproj_w = (const float*)d_in[6];
  const float* qproj_b = (const float*)d_in[7];
  const float* kproj_w = (const float*)d_in[8];
  const float* kproj_b = (const float*)d_in[9];
  float* out = (float*)d_out;

  char* ws = (char*)d_ws;
  unsigned short* qb  = (unsigned short*)(ws);             // [130][130][128]
  unsigned short* vb  = (unsigned short*)(ws + 4326400);   // [1024][128]
  unsigned short* kpb = (unsigned short*)(ws + 4588544);   // [1024][128]
  unsigned short* wb  = (unsigned short*)(ws + 4850688);   // [9][4][128][32]
  unsigned short* wnq = (unsigned short*)(ws + 5145600);   // [128][128]

  prep_k<<<dim3(937), 256, 0, stream>>>(q_in, k_in, v_in, conv_w, normq_w, normk_w,
                                        qproj_w, kproj_w, kproj_b,
                                        qb, vb, kpb, wb, wnq);
  fused_k<<<dim3(256), 256, 0, stream>>>(qb, wb, wnq, qproj_b, kpb, vb, out);
}